// Round 1
// 236.001 us; speedup vs baseline: 1.0636x; 1.0636x over previous
//
#include <hip/hip_runtime.h>

// Problem constants
#define Bc 8
#define Nc 2048
#define Dc 512
#define PH 512            // P*H
#define NN 4194304        // N*N
#define NT 136            // upper-tri 128x128 tiles: 16*17/2

#define BM 128
#define BN 128
#define BK 32

typedef __attribute__((ext_vector_type(8))) short bf16x8;
typedef __attribute__((ext_vector_type(4))) float f32x4;

static __device__ __forceinline__ unsigned short f2b(float x) {
    union { float f; unsigned u; } v; v.f = x;
    unsigned r = v.u + 0x7fffu + ((v.u >> 16) & 1u);   // RNE to bf16
    return (unsigned short)(r >> 16);
}

// async global->LDS DMA, 16 bytes per lane; LDS dest = wave-uniform base + lane*16
static __device__ __forceinline__ void load16_lds(const unsigned short* g, unsigned short* l) {
    __builtin_amdgcn_global_load_lds(
        (const __attribute__((address_space(1))) void*)g,
        (__attribute__((address_space(3))) void*)l,
        16, 0, 0);
}

// ---------------------------------------------------------------------------
// prep: context fp32 -> bf16, W fp32 -> bf16, zero rsum
// ---------------------------------------------------------------------------
__global__ __launch_bounds__(256) void prep_kernel(
    const float* __restrict__ ctx, const float* __restrict__ W,
    unsigned short* __restrict__ Xb, unsigned short* __restrict__ Wb,
    float* __restrict__ rsum) {
    int t = blockIdx.x * 256 + threadIdx.x;
    if (t < 2097152) {
        float4 v = ((const float4*)ctx)[t];
        ushort4 o;
        o.x = f2b(v.x); o.y = f2b(v.y); o.z = f2b(v.z); o.w = f2b(v.w);
        ((ushort4*)Xb)[t] = o;
    }
    if (t < 65536) {
        float4 v = ((const float4*)W)[t];
        ushort4 o;
        o.x = f2b(v.x); o.y = f2b(v.y); o.z = f2b(v.z); o.w = f2b(v.w);
        ((ushort4*)Wb)[t] = o;
    }
    if (t < 4096) {
        float4 z; z.x = 0.f; z.y = 0.f; z.z = 0.f; z.w = 0.f;
        ((float4*)rsum)[t] = z;
    }
}

// ---------------------------------------------------------------------------
// GEMM1: F = relu(Xb @ Wb^T)   Xb:[16384,512] Wb:[512,512]
// grid: (4, 128), block 256
// ---------------------------------------------------------------------------
__global__ __launch_bounds__(256) void gemm1_relu(
    const unsigned short* __restrict__ Xb, const unsigned short* __restrict__ Wb,
    unsigned short* __restrict__ F) {
    __shared__ unsigned short As[BM * BK];
    __shared__ unsigned short Bs[BN * BK];
    const int tid = threadIdx.x;
    const int lane = tid & 63;
    const int wave = tid >> 6;
    const int wm = wave >> 1, wn = wave & 1;
    const int row0 = blockIdx.y * BM;
    const int col0 = blockIdx.x * BN;

    f32x4 acc[4][4] = {};

    for (int k0 = 0; k0 < Dc; k0 += BK) {
#pragma unroll
        for (int j = 0; j < 2; ++j) {
            int e = j * 256 + tid;
            int rr = e >> 2, cc = e & 3;
            load16_lds(&Xb[(size_t)(row0 + rr) * Dc + k0 + cc * 8], &As[e * 8]);
            load16_lds(&Wb[(size_t)(col0 + rr) * Dc + k0 + cc * 8], &Bs[e * 8]);
        }
        __syncthreads();

        bf16x8 af[4], bfr[4];
#pragma unroll
        for (int i = 0; i < 4; ++i) {
            af[i]  = *(const bf16x8*)&As[(wm * 64 + i * 16 + (lane & 15)) * BK + (lane >> 4) * 8];
            bfr[i] = *(const bf16x8*)&Bs[(wn * 64 + i * 16 + (lane & 15)) * BK + (lane >> 4) * 8];
        }
#pragma unroll
        for (int mi = 0; mi < 4; ++mi)
#pragma unroll
            for (int ni = 0; ni < 4; ++ni)
                acc[mi][ni] = __builtin_amdgcn_mfma_f32_16x16x32_bf16(af[mi], bfr[ni], acc[mi][ni], 0, 0, 0);
        __syncthreads();
    }

#pragma unroll
    for (int mi = 0; mi < 4; ++mi) {
#pragma unroll
        for (int ni = 0; ni < 4; ++ni) {
            int col  = col0 + wn * 64 + ni * 16 + (lane & 15);
            int rowb = row0 + wm * 64 + mi * 16 + ((lane >> 4) << 2);
#pragma unroll
            for (int r = 0; r < 4; ++r) {
                float v = fmaxf(acc[mi][ni][r], 0.0f);
                F[(size_t)(rowb + r) * PH + col] = f2b(v);
            }
        }
    }
}

// ---------------------------------------------------------------------------
// NEW PATH pass 3: tri-GEMM, e = exp(S/16-32) stored fp32 per tile, rsum atomics.
// grid: 1088 1-D (b = blk&7 -> batch==XCD affinity under round-robin), block 256.
// ---------------------------------------------------------------------------
__global__ __launch_bounds__(256) void gemm2_store(
    const unsigned short* __restrict__ F, float* __restrict__ rsum,
    float* __restrict__ Ework) {
    __shared__ unsigned short As[BM * BK];
    __shared__ unsigned short Bs[BN * BK];
    const int tid = threadIdx.x;
    const int lane = tid & 63;
    const int wave = tid >> 6;
    const int wm = wave >> 1, wn = wave & 1;
    const int l15 = lane & 15, q = lane >> 4;
    const int b = blockIdx.x & 7;          // batch -> XCD (L2 locality heuristic)
    const int idx = blockIdx.x >> 3;

    // upper-triangular tile index: idx = j*(j+1)/2 + i, i <= j
    int j = 0;
    while (((j + 1) * (j + 2) / 2) <= idx) ++j;
    int i = idx - j * (j + 1) / 2;
    const int row0 = i * BM;
    const int col0 = j * BN;
    const unsigned short* Fb = F + (size_t)b * Nc * PH;

    f32x4 acc[4][4] = {};

    for (int k0 = 0; k0 < PH; k0 += BK) {
#pragma unroll
        for (int jj = 0; jj < 2; ++jj) {
            int e = jj * 256 + tid;
            int rr = e >> 2, cc = e & 3;
            load16_lds(&Fb[(size_t)(row0 + rr) * PH + k0 + cc * 8], &As[e * 8]);
            load16_lds(&Fb[(size_t)(col0 + rr) * PH + k0 + cc * 8], &Bs[e * 8]);
        }
        __syncthreads();

        bf16x8 af[4], bfr[4];
#pragma unroll
        for (int qq = 0; qq < 4; ++qq) {
            af[qq]  = *(const bf16x8*)&As[(wm * 64 + qq * 16 + l15) * BK + q * 8];
            bfr[qq] = *(const bf16x8*)&Bs[(wn * 64 + qq * 16 + l15) * BK + q * 8];
        }
#pragma unroll
        for (int mi = 0; mi < 4; ++mi)
#pragma unroll
            for (int ni = 0; ni < 4; ++ni)
                acc[mi][ni] = __builtin_amdgcn_mfma_f32_16x16x32_bf16(af[mi], bfr[ni], acc[mi][ni], 0, 0, 0);
        __syncthreads();
    }

    // epilogue: e = exp(S/16-32); store tile fp32; accumulate col sums (+ row sums off-diag)
    float* Et = Ework + (size_t)(b * NT + idx) * 16384;

    float csum[4] = {0.f, 0.f, 0.f, 0.f};
    float rsm[4][4];
#pragma unroll
    for (int mi = 0; mi < 4; ++mi)
#pragma unroll
        for (int r = 0; r < 4; ++r) rsm[mi][r] = 0.f;

#pragma unroll
    for (int mi = 0; mi < 4; ++mi) {
#pragma unroll
        for (int ni = 0; ni < 4; ++ni) {
#pragma unroll
            for (int r = 0; r < 4; ++r) {
                float e = __expf(acc[mi][ni][r] * 0.0625f - 32.0f);
                Et[(wm * 64 + mi * 16 + (q << 2) + r) * 128 + wn * 64 + ni * 16 + l15] = e;
                csum[ni] += e;
                rsm[mi][r] += e;
            }
        }
    }
#pragma unroll
    for (int ni = 0; ni < 4; ++ni) {
        float s = csum[ni];
        s += __shfl_xor(s, 16);
        s += __shfl_xor(s, 32);
        if ((lane >> 4) == 0)
            atomicAdd(&rsum[b * Nc + col0 + wn * 64 + ni * 16 + lane], s);
    }
    if (i != j) {
#pragma unroll
        for (int mi = 0; mi < 4; ++mi) {
#pragma unroll
            for (int r = 0; r < 4; ++r) {
                float s = rsm[mi][r];
                s += __shfl_xor(s, 1);
                s += __shfl_xor(s, 2);
                s += __shfl_xor(s, 4);
                s += __shfl_xor(s, 8);
                if ((lane & 15) == 0)
                    atomicAdd(&rsum[b * Nc + row0 + wm * 64 + mi * 16 + ((lane >> 4) << 2) + r], s);
            }
        }
    }
}

// ---------------------------------------------------------------------------
// invr[b,m] = mask[b,m] / rsum[b,m]
// ---------------------------------------------------------------------------
__global__ __launch_bounds__(256) void invr_kernel(
    const float* __restrict__ rsum, const int* __restrict__ mask,
    float* __restrict__ invr) {
    int t = blockIdx.x * 256 + threadIdx.x;
    if (t < Bc * Nc) invr[t] = (float)mask[t] / rsum[t];
}

// ---------------------------------------------------------------------------
// NEW PATH pass 5: pure memory-bound scatter. Per upper-tri tile: read 64 KB
// fp32 e-tile coalesced, write original orientation directly, write mirror
// orientation (i != j) via padded LDS transpose (pad 132 -> 2-way = free).
// grid: 1088 1-D (same b/idx mapping as gemm2_store for L2 reuse), block 256.
// ---------------------------------------------------------------------------
__global__ __launch_bounds__(256) void scatter_out(
    const float* __restrict__ Ework, const float* __restrict__ invr,
    const int* __restrict__ mask, float* __restrict__ out) {
    __shared__ float Ts[32 * 132];
    const int tid = threadIdx.x;
    const int b = blockIdx.x & 7;
    const int idx = blockIdx.x >> 3;

    int j = 0;
    while (((j + 1) * (j + 2) / 2) <= idx) ++j;
    int i = idx - j * (j + 1) / 2;
    const int row0 = i * BM;   // n-range of stored tile rows
    const int col0 = j * BN;   // m-range of stored tile cols

    const float* Et   = Ework + (size_t)(b * NT + idx) * 16384;
    const float* invb = invr + b * Nc;
    const int*   mb   = mask + b * Nc;
    float* outb = out + (size_t)b * NN;

    const int cl = tid >> 3, f0 = tid & 7;   // phase A: 32 rows x 8 lanes/row
    const int mc = tid >> 1, h  = tid & 1;   // phase B: 128 mirror-rows x 2 halves

    for (int ci = 0; ci < 4; ++ci) {         // 32-row chunks of the 128x128 tile
        if (ci) __syncthreads();             // Ts reuse across chunks
        const int r = ci * 32 + cl;
        const int n = row0 + r;
        const float mrow = (float)mb[n];
#pragma unroll
        for (int g = 0; g < 4; ++g) {
            int f = f0 + 8 * g;
            float4 ev = *(const float4*)&Et[r * 128 + 4 * f];
            *(float4*)&Ts[cl * 132 + 4 * f] = ev;
            float4 iv = *(const float4*)&invb[col0 + 4 * f];
            float4 o;
            o.x = ev.x * iv.x * mrow;
            o.y = ev.y * iv.y * mrow;
            o.z = ev.z * iv.z * mrow;
            o.w = ev.w * iv.w * mrow;
            *(float4*)&outb[(size_t)n * Nc + col0 + 4 * f] = o;
        }
        if (i == j) continue;                // diag tile: no mirror (uniform branch)
        __syncthreads();
        const int a = col0 + mc;             // mirror out-row
        const float mcol = (float)mb[a];
        const int nb0 = row0 + ci * 32 + 16 * h;
#pragma unroll
        for (int u = 0; u < 4; ++u) {
            float4 iv = *(const float4*)&invb[nb0 + 4 * u];
            float4 o;
            o.x = Ts[(16 * h + 4 * u + 0) * 132 + mc] * iv.x * mcol;
            o.y = Ts[(16 * h + 4 * u + 1) * 132 + mc] * iv.y * mcol;
            o.z = Ts[(16 * h + 4 * u + 2) * 132 + mc] * iv.z * mcol;
            o.w = Ts[(16 * h + 4 * u + 3) * 132 + mc] * iv.w * mcol;
            *(float4*)&outb[(size_t)a * Nc + nb0 + 4 * u] = o;
        }
    }
}

// ---------------------------------------------------------------------------
// FALLBACK (small workspace): original recompute path, verbatim.
// ---------------------------------------------------------------------------
__global__ __launch_bounds__(256) void gemm2_rsum(
    const unsigned short* __restrict__ F, float* __restrict__ rsum) {
    __shared__ unsigned short As[BM * BK];
    __shared__ unsigned short Bs[BN * BK];
    const int tid = threadIdx.x;
    const int lane = tid & 63;
    const int wave = tid >> 6;
    const int wm = wave >> 1, wn = wave & 1;
    const int b = blockIdx.y;

    int idx = blockIdx.x;
    int j = 0;
    while (((j + 1) * (j + 2) / 2) <= idx) ++j;
    int i = idx - j * (j + 1) / 2;
    const int row0 = i * BM;
    const int col0 = j * BN;
    const unsigned short* Fb = F + (size_t)b * Nc * PH;

    f32x4 acc[4][4] = {};

    for (int k0 = 0; k0 < PH; k0 += BK) {
#pragma unroll
        for (int jj = 0; jj < 2; ++jj) {
            int e = jj * 256 + tid;
            int rr = e >> 2, cc = e & 3;
            load16_lds(&Fb[(size_t)(row0 + rr) * PH + k0 + cc * 8], &As[e * 8]);
            load16_lds(&Fb[(size_t)(col0 + rr) * PH + k0 + cc * 8], &Bs[e * 8]);
        }
        __syncthreads();

        bf16x8 af[4], bfr[4];
#pragma unroll
        for (int q = 0; q < 4; ++q) {
            af[q]  = *(const bf16x8*)&As[(wm * 64 + q * 16 + (lane & 15)) * BK + (lane >> 4) * 8];
            bfr[q] = *(const bf16x8*)&Bs[(wn * 64 + q * 16 + (lane & 15)) * BK + (lane >> 4) * 8];
        }
#pragma unroll
        for (int mi = 0; mi < 4; ++mi)
#pragma unroll
            for (int ni = 0; ni < 4; ++ni)
                acc[mi][ni] = __builtin_amdgcn_mfma_f32_16x16x32_bf16(af[mi], bfr[ni], acc[mi][ni], 0, 0, 0);
        __syncthreads();
    }

    float csum[4] = {0.f, 0.f, 0.f, 0.f};
    float rsm[4][4];
#pragma unroll
    for (int mi = 0; mi < 4; ++mi)
#pragma unroll
        for (int r = 0; r < 4; ++r) rsm[mi][r] = 0.f;

#pragma unroll
    for (int mi = 0; mi < 4; ++mi) {
#pragma unroll
        for (int ni = 0; ni < 4; ++ni) {
#pragma unroll
            for (int r = 0; r < 4; ++r) {
                float e = __expf(acc[mi][ni][r] * 0.0625f - 32.0f);
                csum[ni] += e;
                rsm[mi][r] += e;
            }
        }
    }
#pragma unroll
    for (int ni = 0; ni < 4; ++ni) {
        float s = csum[ni];
        s += __shfl_xor(s, 16);
        s += __shfl_xor(s, 32);
        if ((lane >> 4) == 0)
            atomicAdd(&rsum[b * Nc + col0 + wn * 64 + ni * 16 + lane], s);
    }
    if (i != j) {
#pragma unroll
        for (int mi = 0; mi < 4; ++mi) {
#pragma unroll
            for (int r = 0; r < 4; ++r) {
                float s = rsm[mi][r];
                s += __shfl_xor(s, 1);
                s += __shfl_xor(s, 2);
                s += __shfl_xor(s, 4);
                s += __shfl_xor(s, 8);
                if ((lane & 15) == 0)
                    atomicAdd(&rsum[b * Nc + row0 + wm * 64 + mi * 16 + ((lane >> 4) << 2) + r], s);
            }
        }
    }
}

__global__ __launch_bounds__(256) void gemm2_write_sym(
    const unsigned short* __restrict__ F, const float* __restrict__ invr,
    const int* __restrict__ mask, float* __restrict__ out) {
    __shared__ unsigned short As[BM * BK];
    __shared__ unsigned short Bs[BN * BK];
    __shared__ float Ts[32 * 132];
    const int tid = threadIdx.x;
    const int lane = tid & 63;
    const int wave = tid >> 6;
    const int wm = wave >> 1, wn = wave & 1;
    const int l15 = lane & 15, q = lane >> 4;
    const int b = blockIdx.y;

    int idx = blockIdx.x;
    int j = 0;
    while (((j + 1) * (j + 2) / 2) <= idx) ++j;
    int i = idx - j * (j + 1) / 2;
    const int row0 = i * BM;
    const int col0 = j * BN;
    const unsigned short* Fb = F + (size_t)b * Nc * PH;

    f32x4 acc[4][4] = {};

    for (int k0 = 0; k0 < PH; k0 += BK) {
#pragma unroll
        for (int jj = 0; jj < 2; ++jj) {
            int e = jj * 256 + tid;
            int rr = e >> 2, cc = e & 3;
            load16_lds(&Fb[(size_t)(row0 + rr) * PH + k0 + cc * 8], &As[e * 8]);
            load16_lds(&Fb[(size_t)(col0 + rr) * PH + k0 + cc * 8], &Bs[e * 8]);
        }
        __syncthreads();

        bf16x8 af[4], bfr[4];
#pragma unroll
        for (int qq = 0; qq < 4; ++qq) {
            af[qq]  = *(const bf16x8*)&As[(wm * 64 + qq * 16 + l15) * BK + q * 8];
            bfr[qq] = *(const bf16x8*)&Bs[(wn * 64 + qq * 16 + l15) * BK + q * 8];
        }
#pragma unroll
        for (int mi = 0; mi < 4; ++mi)
#pragma unroll
            for (int ni = 0; ni < 4; ++ni)
                acc[mi][ni] = __builtin_amdgcn_mfma_f32_16x16x32_bf16(af[mi], bfr[ni], acc[mi][ni], 0, 0, 0);
        __syncthreads();
    }

#pragma unroll
    for (int mi = 0; mi < 4; ++mi)
#pragma unroll
        for (int ni = 0; ni < 4; ++ni)
#pragma unroll
            for (int r = 0; r < 4; ++r)
                acc[mi][ni][r] = __expf(acc[mi][ni][r] * 0.0625f - 32.0f);

    float* outb = out + (size_t)b * NN;

    float iv[4];
#pragma unroll
    for (int ni = 0; ni < 4; ++ni)
        iv[ni] = invr[b * Nc + col0 + wn * 64 + ni * 16 + l15];
#pragma unroll
    for (int mi = 0; mi < 4; ++mi) {
        int rowb = row0 + wm * 64 + mi * 16 + (q << 2);
        const int4 mr4 = *(const int4*)&mask[b * Nc + rowb];
        float mr[4] = {(float)mr4.x, (float)mr4.y, (float)mr4.z, (float)mr4.w};
#pragma unroll
        for (int ni = 0; ni < 4; ++ni) {
            int col = col0 + wn * 64 + ni * 16 + l15;
#pragma unroll
            for (int r = 0; r < 4; ++r)
                outb[(size_t)(rowb + r) * Nc + col] = acc[mi][ni][r] * iv[ni] * mr[r];
        }
    }

    if (i != j) {
#pragma unroll
        for (int ci = 0; ci < 4; ++ci) {
            __syncthreads();
            if (wn == (ci >> 1)) {
#pragma unroll
                for (int ni2 = 0; ni2 < 2; ++ni2) {
                    int ni = (ci & 1) * 2 + ni2;
#pragma unroll
                    for (int mi = 0; mi < 4; ++mi) {
                        *(float4*)&Ts[(ni2 * 16 + l15) * 132 + wm * 64 + mi * 16 + (q << 2)] =
                            *(float4*)&acc[mi][ni];
                    }
                }
            }
            __syncthreads();
            int cl = tid >> 3;
            int f0 = tid & 7;
            int nn = col0 + ci * 32 + cl;
            float mrow = (float)mask[b * Nc + nn];
            float* orow = &outb[(size_t)nn * Nc + row0];
#pragma unroll
            for (int g = 0; g < 4; ++g) {
                int f = f0 + g * 8;
                float4 ev  = *(float4*)&Ts[cl * 132 + 4 * f];
                float4 iv4 = *(const float4*)&invr[b * Nc + row0 + 4 * f];
                float4 o;
                o.x = ev.x * iv4.x * mrow;
                o.y = ev.y * iv4.y * mrow;
                o.z = ev.z * iv4.z * mrow;
                o.w = ev.w * iv4.w * mrow;
                *(float4*)&orow[4 * f] = o;
            }
        }
    }
}

// ---------------------------------------------------------------------------
extern "C" void kernel_launch(void* const* d_in, const int* in_sizes, int n_in,
                              void* d_out, int out_size, void* d_ws, size_t ws_size,
                              hipStream_t stream) {
    const float* ctx  = (const float*)d_in[0];   // [8,2048,512] fp32
    const float* W    = (const float*)d_in[1];   // [16,32,512] fp32
    const int*   mask = (const int*)d_in[2];     // [8,2048] int32
    float* out = (float*)d_out;                  // [8,2048,2048] fp32

    char* ws = (char*)d_ws;

    // New-path layout: Ework(fp32, 1088 tiles * 64KB = 71303168) overlays dead Xb/Wb.
    //   [0 .. 71303168)           Ework   (Xb at 0, Wb at 16777216 live only until gemm1)
    //   [71303168 .. 88080384)    F (bf16, 16384x512)
    //   [88080384 .. 88145920)    rsum
    //   [88145920 .. 88211456)    invr
    const size_t NEED = 88211456;

    if (ws_size >= NEED) {
        float*          Ework = (float*)ws;
        unsigned short* Xb    = (unsigned short*)ws;
        unsigned short* Wb    = (unsigned short*)(ws + 16777216);
        unsigned short* F     = (unsigned short*)(ws + 71303168);
        float*          rsum  = (float*)(ws + 88080384);
        float*          invr  = (float*)(ws + 88145920);

        prep_kernel<<<8192, 256, 0, stream>>>(ctx, W, Xb, Wb, rsum);
        gemm1_relu<<<dim3(4, 128), 256, 0, stream>>>(Xb, Wb, F);
        gemm2_store<<<1088, 256, 0, stream>>>(F, rsum, Ework);      // tri-GEMM + e-store + rsum
        invr_kernel<<<64, 256, 0, stream>>>(rsum, mask, invr);
        scatter_out<<<1088, 256, 0, stream>>>(Ework, invr, mask, out);  // pure-BW pass
    } else {
        // fallback: original recompute path (needs ~34.2 MB)
        unsigned short* Xb = (unsigned short*)ws;
        unsigned short* Wb = (unsigned short*)(ws + 16777216);
        unsigned short* F  = (unsigned short*)(ws + 16777216 + 524288);
        float* rsum        = (float*)(ws + 16777216 + 524288 + 16777216);
        float* invr        = (float*)(ws + 16777216 + 524288 + 16777216 + 65536);

        prep_kernel<<<8192, 256, 0, stream>>>(ctx, W, Xb, Wb, rsum);
        gemm1_relu<<<dim3(4, 128), 256, 0, stream>>>(Xb, Wb, F);
        gemm2_rsum<<<dim3(136, 8), 256, 0, stream>>>(F, rsum);
        invr_kernel<<<64, 256, 0, stream>>>(rsum, mask, invr);
        gemm2_write_sym<<<dim3(136, 8), 256, 0, stream>>>(F, invr, mask, out);
    }
}